// Round 5
// baseline (169.986 us; speedup 1.0000x reference)
//
#include <hip/hip_runtime.h>
#include <stdint.h>
#include <math.h>

// InformerLayer on MI355X — round 5.
// h[t,c] = x_t*mlp_w[c] + mlp_b[c]  => attention collapses to scalar math on x;
// FFN is the only real GEMM -> bf16 MFMA (16x16x32), fused mega-kernel.
// Round-5: round-4's K-split wave-private GEMM pipeline, with the LDS-overflow
// in the K-partial reduction fixed: partials are reduced in TWO phases
// (rows 0-15, then 16-31) through the tbuf wave slots. 6 barriers total.

#define EPSF 1e-5f

typedef short bf16x8 __attribute__((ext_vector_type(8)));
typedef float f32x4  __attribute__((ext_vector_type(4)));

__device__ __forceinline__ unsigned short f2bf(float f) {
  union { float f; unsigned u; } v; v.f = f;
  unsigned r = v.u + 0x7FFFu + ((v.u >> 16) & 1u);
  return (unsigned short)(r >> 16);
}
__device__ __forceinline__ float bf2f(unsigned short u) {
  union { unsigned u; float f; } v; v.u = ((unsigned)u) << 16;
  return v.f;
}
__device__ __forceinline__ float waveSum(float v) {
  #pragma unroll
  for (int m = 32; m > 0; m >>= 1) v += __shfl_xor(v, m);
  return v;
}

// ---------------------------------------------------------------------------
// threefry2x32 with key (0, 42) == jax.random.key(42)
// ---------------------------------------------------------------------------
__device__ __forceinline__ void threefry2x32_k42(uint32_t& x0, uint32_t& x1) {
  const uint32_t ks0 = 0u, ks1 = 42u, ks2 = 0u ^ 42u ^ 0x1BD11BDAu;
  x0 += ks0; x1 += ks1;
#define TF_R(d) { x0 += x1; x1 = (x1 << d) | (x1 >> (32 - d)); x1 ^= x0; }
  TF_R(13) TF_R(15) TF_R(26) TF_R(6)  x0 += ks1; x1 += ks2 + 1u;
  TF_R(17) TF_R(29) TF_R(16) TF_R(24) x0 += ks2; x1 += ks0 + 2u;
  TF_R(13) TF_R(15) TF_R(26) TF_R(6)  x0 += ks0; x1 += ks1 + 3u;
  TF_R(17) TF_R(29) TF_R(16) TF_R(24) x0 += ks1; x1 += ks2 + 4u;
  TF_R(13) TF_R(15) TF_R(26) TF_R(6)  x0 += ks2; x1 += ks0 + 5u;
#undef TF_R
}

// ---------------------------------------------------------------------------
// Kernel A (grid 32): block 0: idxT + folded constants; all blocks: w -> bf16.
// cst layout (floats): 0 Aq[128] |128 cq |256 Ak |384 ck |512 Av |640 cv |
//   768 alpha[8] |776 beta[8] |784 gamma[8] |792 delta[8] |
//   800 Wv[8][128] |1824 ccol[128]
// ---------------------------------------------------------------------------
__global__ __launch_bounds__(256) void setup_kernel(
    const float* __restrict__ mlp_w, const float* __restrict__ mlp_b,
    const float* __restrict__ wq, const float* __restrict__ bq,
    const float* __restrict__ wk, const float* __restrict__ bk,
    const float* __restrict__ wv, const float* __restrict__ bv,
    const float* __restrict__ wo, const float* __restrict__ bo,
    const float* __restrict__ w1, const float* __restrict__ w2,
    int* __restrict__ idxT, float* __restrict__ cst,
    unsigned short* __restrict__ w1bf, unsigned short* __restrict__ w2bf) {
  int tid = threadIdx.x;
  {
    int gid = blockIdx.x * 256 + tid;        // 0..8191, 16 elems each
    int base = gid * 16;
    const float* src; unsigned short* dst; int off;
    if (base < 65536) { src = w1; dst = w1bf; off = base; }
    else              { src = w2; dst = w2bf; off = base - 65536; }
    #pragma unroll 4
    for (int k = 0; k < 16; k++) dst[off + k] = f2bf(src[off + k]);
  }
  if (blockIdx.x != 0) return;
  for (int p = tid; p < 2304; p += 256) {
    uint32_t a = (uint32_t)p, bb = (uint32_t)(p + 2304);
    threefry2x32_k42(a, bb);
    int l0 = p / 18, j0 = p - l0 * 18;
    int p2 = p + 2304;
    int l1 = p2 / 18, j1 = p2 - l1 * 18;
    idxT[j0 * 256 + l0] = (int)(a & 0xFFu);
    idxT[j1 * 256 + l1] = (int)(bb & 0xFFu);
  }
  if (tid < 128) {
    float aq = 0.f, cq_ = 0.f, ak = 0.f, ck_ = 0.f, av = 0.f, cv_ = 0.f;
    for (int c = 0; c < 128; c++) {
      float w = mlp_w[c], bb = mlp_b[c];
      float q = wq[tid * 128 + c], k = wk[tid * 128 + c], v = wv[tid * 128 + c];
      aq += q * w; cq_ += q * bb;
      ak += k * w; ck_ += k * bb;
      av += v * w; cv_ += v * bb;
    }
    cst[0   + tid] = aq;
    cst[128 + tid] = cq_ + bq[tid];
    cst[256 + tid] = ak;
    cst[384 + tid] = ck_ + bk[tid];
    cst[512 + tid] = av;
    cst[640 + tid] = cv_ + bv[tid];
  }
  __syncthreads();
  if (tid < 8) {
    float a = 0.f, b = 0.f, g = 0.f, d = 0.f;
    for (int e = 0; e < 16; e++) {
      int j = tid * 16 + e;
      float Aq = cst[j], Cq = cst[128 + j], Ak = cst[256 + j], Ck = cst[384 + j];
      a += Aq * Ak; b += Aq * Ck; g += Cq * Ak; d += Cq * Ck;
    }
    cst[768 + tid] = a; cst[776 + tid] = b; cst[784 + tid] = g; cst[792 + tid] = d;
  }
  if (tid < 128) {
    float oc = 0.f;
    for (int h = 0; h < 8; h++) {
      float s = 0.f;
      for (int e = 0; e < 16; e++) {
        float w = wo[tid * 128 + h * 16 + e];
        s  += w * cst[512 + h * 16 + e];   // Av
        oc += w * cst[640 + h * 16 + e];   // cv
      }
      cst[800 + h * 128 + tid] = s;        // Wv[h][i]
    }
    cst[1824 + tid] = oc + bo[tid] + mlp_b[tid];  // ccol
  }
}

// ---------------------------------------------------------------------------
// Kernel B: per (seq, head-pair). score(l,s) = a*x_l*x_s + b*x_l + g*x_s + d.
// Top-18 via vectorized rank counting; softmax rows on half-wave groups.
// ---------------------------------------------------------------------------
__global__ __launch_bounds__(256) void attn_kernel(
    const float* __restrict__ x, const int* __restrict__ idxT,
    const float* __restrict__ cst, float* __restrict__ g) {
  __shared__ float xr[256];
  __shared__ float Mb[512];     // [hl][l]
  __shared__ float selv[512];   // [hl][l]
  __shared__ float rsum[4], rmax[4], rmin[4];
  __shared__ int   items[64];
  __shared__ float witem[64];
  __shared__ int   cnt;
  int tid = threadIdx.x, lane = tid & 63, w = tid >> 6;
  int seq = blockIdx.x >> 2, hg = blockIdx.x & 3;
  if (tid == 0) cnt = 0;
  float xv = x[seq * 256 + tid];
  xr[tid] = xv;
  float s = waveSum(xv);
  float mx = xv, mn = xv;
  #pragma unroll
  for (int m = 32; m > 0; m >>= 1) {
    mx = fmaxf(mx, __shfl_xor(mx, m));
    mn = fminf(mn, __shfl_xor(mn, m));
  }
  if (lane == 0) { rsum[w] = s; rmax[w] = mx; rmin[w] = mn; }
  __syncthreads();
  float meanx = (rsum[0] + rsum[1] + rsum[2] + rsum[3]) * (1.0f / 256.0f);
  float maxx = fmaxf(fmaxf(rmax[0], rmax[1]), fmaxf(rmax[2], rmax[3]));
  float minx = fminf(fminf(rmin[0], rmin[1]), fminf(rmin[2], rmin[3]));
  int l32 = tid & 31, grp = tid >> 5;
  float xs8[8];
  #pragma unroll
  for (int k = 0; k < 8; k++) xs8[k] = xr[l32 + k * 32];
  float mx18 = -INFINITY, mn18 = INFINITY, s18 = 0.f;
  #pragma unroll 3
  for (int j = 0; j < 18; j++) {
    float xs = xr[idxT[j * 256 + tid]];
    mx18 = fmaxf(mx18, xs); mn18 = fminf(mn18, xs); s18 += xs;
  }
  int h0 = hg * 2, h1 = h0 + 1;
  float al0 = cst[768 + h0], be0 = cst[776 + h0], ga0 = cst[784 + h0], de0 = cst[792 + h0];
  float al1 = cst[768 + h1], be1 = cst[776 + h1], ga1 = cst[784 + h1], de1 = cst[792 + h1];
  float ac0 = fmaf(al0, xv, ga0), cc0 = fmaf(be0, xv, de0);
  float ac1 = fmaf(al1, xv, ga1), cc1 = fmaf(be1, xv, de1);
  float M0 = ((ac0 >= 0.f ? ac0 * mx18 : ac0 * mn18) + cc0)
           - (fmaf(ac0, s18, 18.f * cc0)) * (1.0f / 256.0f);
  float M1 = ((ac1 >= 0.f ? ac1 * mx18 : ac1 * mn18) + cc1)
           - (fmaf(ac1, s18, 18.f * cc1)) * (1.0f / 256.0f);
  Mb[tid] = M0; Mb[256 + tid] = M1;
  __syncthreads();
  int r0 = 0, r1 = 0;
  const float4* Mb4 = (const float4*)Mb;
  #pragma unroll 4
  for (int j4 = 0; j4 < 64; j4++) {
    float4 a = Mb4[j4], bb = Mb4[64 + j4];
    int base = j4 * 4;
    r0 += (a.x > M0) || (a.x == M0 && base     < tid);
    r0 += (a.y > M0) || (a.y == M0 && base + 1 < tid);
    r0 += (a.z > M0) || (a.z == M0 && base + 2 < tid);
    r0 += (a.w > M0) || (a.w == M0 && base + 3 < tid);
    r1 += (bb.x > M1) || (bb.x == M1 && base     < tid);
    r1 += (bb.y > M1) || (bb.y == M1 && base + 1 < tid);
    r1 += (bb.z > M1) || (bb.z == M1 && base + 2 < tid);
    r1 += (bb.w > M1) || (bb.w == M1 && base + 3 < tid);
  }
  selv[tid] = meanx; selv[256 + tid] = meanx;
  if (r0 < 18) { int p = atomicAdd(&cnt, 1); items[p] = tid;       witem[p] = 0.25f * ac0; }
  if (r1 < 18) { int p = atomicAdd(&cnt, 1); items[p] = 256 + tid; witem[p] = 0.25f * ac1; }
  __syncthreads();
  int nIt = cnt;
  for (int i = grp; i < nIt; i += 8) {
    int it = items[i]; float wv = witem[i];
    float m0 = (wv >= 0.f) ? wv * maxx : wv * minx;
    float S1 = 0.f, Sx = 0.f;
    #pragma unroll
    for (int k = 0; k < 8; k++) {
      float e = __expf(fmaf(wv, xs8[k], -m0));
      S1 += e; Sx = fmaf(xs8[k], e, Sx);
    }
    #pragma unroll
    for (int m = 16; m > 0; m >>= 1) {
      S1 += __shfl_xor(S1, m); Sx += __shfl_xor(Sx, m);
    }
    if (l32 == 0) selv[it] = Sx / S1;
  }
  __syncthreads();
  float2 gv; gv.x = selv[tid]; gv.y = selv[256 + tid];
  *(float2*)&g[(size_t)((seq << 8) + tid) * 8 + hg * 2] = gv;
}

// ---------------------------------------------------------------------------
// Mega-kernel round 5: one block per (b, t), 32 rows (the N dim), 4 waves.
// Wave w owns f-slice [w*128,(w+1)*128): GEMM1 (all 32 rows) -> relu ->
// transpose via wave-PRIVATE LDS slot -> GEMM2 K-slice over full c=128.
// No barriers in the GEMM span. Cross-wave K-partial reduce (bf16) in TWO
// phases through tbuf wave slots (rows 0-15, then 16-31); x1s never reused.
// MFMA 16x16x32 bf16: A[m=lane&15][k=quad*8+j], B[k=quad*8+j][n=lane&15],
// C/D: col=lane&15, row=quad*4+reg.
// ---------------------------------------------------------------------------
__global__ __launch_bounds__(256, 3) void mega_kernel(
    const float* __restrict__ x, const float* __restrict__ g,
    const float* __restrict__ cst, const float* __restrict__ mlp_w,
    const unsigned short* __restrict__ w1bf, const float* __restrict__ b1,
    const unsigned short* __restrict__ w2bf, const float* __restrict__ b2,
    const float* __restrict__ ln1g, const float* __restrict__ ln1b,
    const float* __restrict__ ln2g, const float* __restrict__ ln2b,
    float* __restrict__ out) {
  __shared__ unsigned short x1s[32 * 136];   // 8704 B (LN1 output, kept intact)
  __shared__ unsigned short tbuf[4 * 2304];  // 18432 B; transpose, then zred
  __shared__ float psum[512];                // 2048 B
  int tid = threadIdx.x, lane = tid & 63, w = tid >> 6;
  int col = lane & 15, quad = lane >> 4;
  int b = blockIdx.x >> 8, t = blockIdx.x & 255;
  unsigned short* tb = tbuf + w * 2304;

  // ---- LN1: wave w rows w*8..w*8+7, batched 4 rows for ILP ----
  {
    int c0 = lane << 1;
    float mwa = mlp_w[c0], mwb = mlp_w[c0 | 1];
    float cca = cst[1824 + c0], ccb = cst[1824 + (c0 | 1)];
    float wva[8], wvb[8];
    #pragma unroll
    for (int h = 0; h < 8; h++) {
      wva[h] = cst[800 + h * 128 + c0];
      wvb[h] = cst[800 + h * 128 + (c0 | 1)];
    }
    float g1a = ln1g[c0], g1b = ln1g[c0 | 1];
    float e1a = ln1b[c0], e1b = ln1b[c0 | 1];
    #pragma unroll
    for (int bt = 0; bt < 2; bt++) {
      float xv4[4]; float4 gA[4], gB[4];
      #pragma unroll
      for (int k = 0; k < 4; k++) {
        int n = w * 8 + bt * 4 + k;
        int tok = ((b * 32 + n) << 8) + t;
        xv4[k] = x[tok];
        gA[k] = *(const float4*)(g + (size_t)tok * 8);
        gB[k] = *(const float4*)(g + (size_t)tok * 8 + 4);
      }
      float ra[4], rb[4], su[4];
      #pragma unroll
      for (int k = 0; k < 4; k++) {
        float a_ = fmaf(xv4[k], mwa, cca), b_ = fmaf(xv4[k], mwb, ccb);
        a_ = fmaf(gA[k].x, wva[0], a_); b_ = fmaf(gA[k].x, wvb[0], b_);
        a_ = fmaf(gA[k].y, wva[1], a_); b_ = fmaf(gA[k].y, wvb[1], b_);
        a_ = fmaf(gA[k].z, wva[2], a_); b_ = fmaf(gA[k].z, wvb[2], b_);
        a_ = fmaf(gA[k].w, wva[3], a_); b_ = fmaf(gA[k].w, wvb[3], b_);
        a_ = fmaf(gB[k].x, wva[4], a_); b_ = fmaf(gB[k].x, wvb[4], b_);
        a_ = fmaf(gB[k].y, wva[5], a_); b_ = fmaf(gB[k].y, wvb[5], b_);
        a_ = fmaf(gB[k].z, wva[6], a_); b_ = fmaf(gB[k].z, wvb[6], b_);
        a_ = fmaf(gB[k].w, wva[7], a_); b_ = fmaf(gB[k].w, wvb[7], b_);
        ra[k] = a_; rb[k] = b_; su[k] = a_ + b_;
      }
      #pragma unroll
      for (int m = 32; m > 0; m >>= 1) {
        su[0] += __shfl_xor(su[0], m); su[1] += __shfl_xor(su[1], m);
        su[2] += __shfl_xor(su[2], m); su[3] += __shfl_xor(su[3], m);
      }
      float vs[4], da[4], db[4];
      #pragma unroll
      for (int k = 0; k < 4; k++) {
        float mu = su[k] * (1.0f / 128.0f);
        da[k] = ra[k] - mu; db[k] = rb[k] - mu;
        vs[k] = da[k] * da[k] + db[k] * db[k];
      }
      #pragma unroll
      for (int m = 32; m > 0; m >>= 1) {
        vs[0] += __shfl_xor(vs[0], m); vs[1] += __shfl_xor(vs[1], m);
        vs[2] += __shfl_xor(vs[2], m); vs[3] += __shfl_xor(vs[3], m);
      }
      #pragma unroll
      for (int k = 0; k < 4; k++) {
        int n = w * 8 + bt * 4 + k;
        float inv = rsqrtf(vs[k] * (1.0f / 128.0f) + EPSF);
        unsigned int pa = f2bf(da[k] * inv * g1a + e1a);
        unsigned int pb = f2bf(db[k] * inv * g1b + e1b);
        *(unsigned int*)&x1s[n * 136 + c0] = pa | (pb << 16);
      }
    }
  }
  __syncthreads();   // x1s complete

  // ---- wave-private GEMM1 -> relu -> transpose -> GEMM2 (K-split) ----
  float b1v[2][4];
  #pragma unroll
  for (int ch = 0; ch < 2; ch++)
    #pragma unroll
    for (int ft = 0; ft < 4; ft++)
      b1v[ch][ft] = b1[w * 128 + ch * 64 + ft * 16 + col];

  f32x4 acc2[2][8];
  #pragma unroll
  for (int i = 0; i < 2; i++)
    #pragma unroll
    for (int j = 0; j < 8; j++) acc2[i][j] = (f32x4){0.f, 0.f, 0.f, 0.f};

  #pragma unroll
  for (int ch = 0; ch < 2; ch++) {
    int fbase = w * 128 + ch * 64;
    f32x4 acc1[2][4];
    #pragma unroll
    for (int i = 0; i < 2; i++)
      #pragma unroll
      for (int j = 0; j < 4; j++) acc1[i][j] = (f32x4){0.f, 0.f, 0.f, 0.f};
    #pragma unroll
    for (int ks = 0; ks < 4; ks++) {
      bf16x8 a0 = *(const bf16x8*)&x1s[col * 136 + ks * 32 + quad * 8];
      bf16x8 a1 = *(const bf16x8*)&x1s[(16 + col) * 136 + ks * 32 + quad * 8];
      #pragma unroll
      for (int ft = 0; ft < 4; ft++) {
        int f = fbase + ft * 16 + col;
        bf16x8 bw = *(const bf16x8*)(w1bf + f * 128 + ks * 32 + quad * 8);
        acc1[0][ft] = __builtin_amdgcn_mfma_f32_16x16x32_bf16(a0, bw, acc1[0][ft], 0, 0, 0);
        acc1[1][ft] = __builtin_amdgcn_mfma_f32_16x16x32_bf16(a1, bw, acc1[1][ft], 0, 0, 0);
      }
    }
    // relu + bias -> wave-private transpose slot (C-layout -> A-layout)
    #pragma unroll
    for (int ft = 0; ft < 4; ft++) {
      #pragma unroll
      for (int rg = 0; rg < 2; rg++) {
        #pragma unroll
        for (int r = 0; r < 4; r++) {
          float vv = fmaxf(acc1[rg][ft][r] + b1v[ch][ft], 0.f);
          tb[(rg * 16 + quad * 4 + r) * 72 + ft * 16 + col] = f2bf(vv);
        }
      }
    }
    // GEMM2 partial: K-slice = this wave's f-slice chunk, full c=128
    #pragma unroll
    for (int kk = 0; kk < 2; kk++) {
      bf16x8 a0 = *(const bf16x8*)&tb[col * 72 + kk * 32 + quad * 8];
      bf16x8 a1 = *(const bf16x8*)&tb[(16 + col) * 72 + kk * 32 + quad * 8];
      int kg = fbase + kk * 32 + quad * 8;
      #pragma unroll
      for (int tc = 0; tc < 8; tc++) {
        int c = tc * 16 + col;
        bf16x8 bw = *(const bf16x8*)(w2bf + c * 512 + kg);
        acc2[0][tc] = __builtin_amdgcn_mfma_f32_16x16x32_bf16(a0, bw, acc2[0][tc], 0, 0, 0);
        acc2[1][tc] = __builtin_amdgcn_mfma_f32_16x16x32_bf16(a1, bw, acc2[1][tc], 0, 0, 0);
      }
    }
  }

  // ---- epilogue: two-phase cross-wave K-partial reduce + LN2 + n-sum ----
  int row16 = tid >> 4, c8 = (tid & 15) << 3;
  float b2v[8], g2v[8], e2v[8];
  {
    float4 a0 = *(const float4*)(b2 + c8),  a1 = *(const float4*)(b2 + c8 + 4);
    float4 b0 = *(const float4*)(ln2g + c8), b1_ = *(const float4*)(ln2g + c8 + 4);
    float4 c0 = *(const float4*)(ln2b + c8), c1 = *(const float4*)(ln2b + c8 + 4);
    b2v[0]=a0.x; b2v[1]=a0.y; b2v[2]=a0.z; b2v[3]=a0.w;
    b2v[4]=a1.x; b2v[5]=a1.y; b2v[6]=a1.z; b2v[7]=a1.w;
    g2v[0]=b0.x; g2v[1]=b0.y; g2v[2]=b0.z; g2v[3]=b0.w;
    g2v[4]=b1_.x; g2v[5]=b1_.y; g2v[6]=b1_.z; g2v[7]=b1_.w;
    e2v[0]=c0.x; e2v[1]=c0.y; e2v[2]=c0.z; e2v[3]=c0.w;
    e2v[4]=c1.x; e2v[5]=c1.y; e2v[6]=c1.z; e2v[7]=c1.w;
  }
  // residual (x1s is never overwritten; safe without extra barriers)
  float res[2][8];
  #pragma unroll
  for (int p = 0; p < 2; p++) {
    bf16x8 rv = *(const bf16x8*)&x1s[(p * 16 + row16) * 136 + c8];
    #pragma unroll
    for (int k = 0; k < 8; k++) res[p][k] = bf2f((unsigned short)rv[k]);
  }

  #pragma unroll
  for (int p = 0; p < 2; p++) {
    if (p) __syncthreads();   // phase-0 reads of tbuf done before overwrite
    // write this wave's partial for rows p*16..p*16+15 (local rows 0..15)
    #pragma unroll
    for (int tc = 0; tc < 8; tc++) {
      #pragma unroll
      for (int r = 0; r < 4; r++)
        tb[(quad * 4 + r) * 136 + tc * 16 + col] = f2bf(acc2[p][tc][r]);
    }
    __syncthreads();          // all 4 wave-partials visible
    float z[8];
    #pragma unroll
    for (int k = 0; k < 8; k++) z[k] = b2v[k] + res[p][k];
    #pragma unroll
    for (int ws = 0; ws < 4; ws++) {
      bf16x8 v = *(const bf16x8*)&tbuf[ws * 2304 + row16 * 136 + c8];
      #pragma unroll
      for (int k = 0; k < 8; k++) z[k] += bf2f((unsigned short)v[k]);
    }
    float s = 0.f;
    #pragma unroll
    for (int k = 0; k < 8; k++) s += z[k];
    #pragma unroll
    for (int m = 1; m <= 8; m <<= 1) s += __shfl_xor(s, m);
    float mu = s * (1.0f / 128.0f);
    float q = 0.f;
    #pragma unroll
    for (int k = 0; k < 8; k++) { float d = z[k] - mu; q += d * d; }
    #pragma unroll
    for (int m = 1; m <= 8; m <<= 1) q += __shfl_xor(q, m);
    float inv = rsqrtf(q * (1.0f / 128.0f) + EPSF);
    float o[8];
    #pragma unroll
    for (int k = 0; k < 8; k++) o[k] = (z[k] - mu) * inv * g2v[k] + e2v[k];
    // sum over this wave's 4 rows (lane bits 16, 32)
    #pragma unroll
    for (int k = 0; k < 8; k++) {
      o[k] += __shfl_xor(o[k], 16);
      o[k] += __shfl_xor(o[k], 32);
    }
    if (lane < 16) {
      float* pp = &psum[w * 128 + lane * 8];
      if (p == 0) {
        #pragma unroll
        for (int k = 0; k < 8; k++) pp[k] = o[k];
      } else {
        #pragma unroll
        for (int k = 0; k < 8; k++) pp[k] += o[k];
      }
    }
  }
  __syncthreads();
  if (tid < 128) {
    float v = psum[tid] + psum[128 + tid] + psum[256 + tid] + psum[384 + tid];
    out[(size_t)(b * 128 + tid) * 256 + t] = v;
  }
}

// ---------------------------------------------------------------------------
extern "C" void kernel_launch(void* const* d_in, const int* in_sizes, int n_in,
                              void* d_out, int out_size, void* d_ws, size_t ws_size,
                              hipStream_t stream) {
  (void)in_sizes; (void)n_in; (void)out_size; (void)ws_size;
  const float* x    = (const float*)d_in[0];
  const float* mlpw = (const float*)d_in[1];
  const float* mlpb = (const float*)d_in[2];
  const float* wq   = (const float*)d_in[3];
  const float* bq   = (const float*)d_in[4];
  const float* wk   = (const float*)d_in[5];
  const float* bk   = (const float*)d_in[6];
  const float* wv   = (const float*)d_in[7];
  const float* bv   = (const float*)d_in[8];
  const float* wo   = (const float*)d_in[9];
  const float* bo   = (const float*)d_in[10];
  const float* w1   = (const float*)d_in[11];
  const float* b1   = (const float*)d_in[12];
  const float* w2   = (const float*)d_in[13];
  const float* b2   = (const float*)d_in[14];
  const float* ln1g = (const float*)d_in[15];
  const float* ln1b = (const float*)d_in[16];
  const float* ln2g = (const float*)d_in[17];
  const float* ln2b = (const float*)d_in[18];

  char* ws = (char*)d_ws;
  int*            idxT = (int*)(ws);                       // 18,432 B
  float*          cst  = (float*)(ws + 20480);             //  7,808 B
  unsigned short* w1bf = (unsigned short*)(ws + 32768);    // 131,072 B
  unsigned short* w2bf = (unsigned short*)(ws + 163840);   // 131,072 B
  float*          gbuf = (float*)(ws + 294912);            // 1 MB
  float*          outp = (float*)d_out;

  hipLaunchKernelGGL(setup_kernel, dim3(32), dim3(256), 0, stream,
                     mlpw, mlpb, wq, bq, wk, bk, wv, bv, wo, bo, w1, w2,
                     idxT, cst, w1bf, w2bf);
  hipLaunchKernelGGL(attn_kernel, dim3(512), dim3(256), 0, stream,
                     x, idxT, cst, gbuf);
  hipLaunchKernelGGL(mega_kernel, dim3(1024), dim3(256), 0, stream,
                     x, gbuf, cst, mlpw, w1bf, b1, w2bf, b2,
                     ln1g, ln1b, ln2g, ln2b, outp);
}

// Round 6
// 151.098 us; speedup vs baseline: 1.1250x; 1.1250x over previous
//
#include <hip/hip_runtime.h>
#include <stdint.h>
#include <math.h>

// InformerLayer on MI355X — round 6.
// h[t,c] = x_t*mlp_w[c] + mlp_b[c]  => attention collapses to scalar math on x;
// FFN is the only real GEMM -> bf16 MFMA (16x16x32), fused mega-kernel.
// Round-6: weights pre-swizzled into MFMA B-FRAGMENT ORDER in setup, so every
// weight load in mega is a fully-coalesced 1KB wave load (was a 16-line
// gather: f*128 / c*512 strides — the round 2-5 MfmaUtil~6% stall source).

#define EPSF 1e-5f

typedef short bf16x8 __attribute__((ext_vector_type(8)));
typedef float f32x4  __attribute__((ext_vector_type(4)));

__device__ __forceinline__ unsigned short f2bf(float f) {
  union { float f; unsigned u; } v; v.f = f;
  unsigned r = v.u + 0x7FFFu + ((v.u >> 16) & 1u);
  return (unsigned short)(r >> 16);
}
__device__ __forceinline__ float bf2f(unsigned short u) {
  union { unsigned u; float f; } v; v.u = ((unsigned)u) << 16;
  return v.f;
}
__device__ __forceinline__ float waveSum(float v) {
  #pragma unroll
  for (int m = 32; m > 0; m >>= 1) v += __shfl_xor(v, m);
  return v;
}

// ---------------------------------------------------------------------------
// threefry2x32 with key (0, 42) == jax.random.key(42)
// ---------------------------------------------------------------------------
__device__ __forceinline__ void threefry2x32_k42(uint32_t& x0, uint32_t& x1) {
  const uint32_t ks0 = 0u, ks1 = 42u, ks2 = 0u ^ 42u ^ 0x1BD11BDAu;
  x0 += ks0; x1 += ks1;
#define TF_R(d) { x0 += x1; x1 = (x1 << d) | (x1 >> (32 - d)); x1 ^= x0; }
  TF_R(13) TF_R(15) TF_R(26) TF_R(6)  x0 += ks1; x1 += ks2 + 1u;
  TF_R(17) TF_R(29) TF_R(16) TF_R(24) x0 += ks2; x1 += ks0 + 2u;
  TF_R(13) TF_R(15) TF_R(26) TF_R(6)  x0 += ks0; x1 += ks1 + 3u;
  TF_R(17) TF_R(29) TF_R(16) TF_R(24) x0 += ks1; x1 += ks2 + 4u;
  TF_R(13) TF_R(15) TF_R(26) TF_R(6)  x0 += ks2; x1 += ks0 + 5u;
#undef TF_R
}

// ---------------------------------------------------------------------------
// Kernel A (grid 64): all blocks: swizzle w1/w2 into MFMA B-fragment order
// (bf16). Fragment layouts (8 bf16 each):
//   w1s frag F = (((w*2+ch)*4+ks)*4+ft)*64+lane :
//        w1[f=w*128+ch*64+ft*16+(lane&15)][k=ks*32+(lane>>4)*8 .. +8]
//   w2s frag G = (((w*2+ch)*2+kk)*8+tc)*64+lane :
//        w2[c=tc*16+(lane&15)][k=w*128+ch*64+kk*32+(lane>>4)*8 .. +8]
// Block 0 additionally: idxT (threefry) + folded constants.
// cst layout (floats): 0 Aq[128] |128 cq |256 Ak |384 ck |512 Av |640 cv |
//   768 alpha[8] |776 beta[8] |784 gamma[8] |792 delta[8] |
//   800 Wv[8][128] |1824 ccol[128]
// ---------------------------------------------------------------------------
__global__ __launch_bounds__(256) void setup_kernel(
    const float* __restrict__ mlp_w, const float* __restrict__ mlp_b,
    const float* __restrict__ wq, const float* __restrict__ bq,
    const float* __restrict__ wk, const float* __restrict__ bk,
    const float* __restrict__ wv, const float* __restrict__ bv,
    const float* __restrict__ wo, const float* __restrict__ bo,
    const float* __restrict__ w1, const float* __restrict__ w2,
    int* __restrict__ idxT, float* __restrict__ cst,
    unsigned short* __restrict__ w1s, unsigned short* __restrict__ w2s) {
  int tid = threadIdx.x;
  {
    int fid = blockIdx.x * 256 + tid;        // 0..16383, one fragment each
    const float* s;
    unsigned short* d;
    if (fid < 8192) {
      int lane = fid & 63; int tmp = fid >> 6;
      int ft = tmp & 3; tmp >>= 2;
      int ks = tmp & 3; tmp >>= 2;
      int ch = tmp & 1; int w = tmp >> 1;
      int col = lane & 15, quad = lane >> 4;
      int f = w * 128 + ch * 64 + ft * 16 + col;
      int k = ks * 32 + quad * 8;
      s = w1 + f * 128 + k;
      d = w1s + fid * 8;
    } else {
      int G = fid - 8192;
      int lane = G & 63; int tmp = G >> 6;
      int tc = tmp & 7; tmp >>= 3;
      int kk = tmp & 1; tmp >>= 1;
      int ch = tmp & 1; int w = tmp >> 1;
      int col = lane & 15, quad = lane >> 4;
      int c = tc * 16 + col;
      int k = w * 128 + ch * 64 + kk * 32 + quad * 8;
      s = w2 + c * 512 + k;
      d = w2s + G * 8;
    }
    float4 v0 = *(const float4*)s, v1 = *(const float4*)(s + 4);
    uint4 pk;
    pk.x = (unsigned)f2bf(v0.x) | ((unsigned)f2bf(v0.y) << 16);
    pk.y = (unsigned)f2bf(v0.z) | ((unsigned)f2bf(v0.w) << 16);
    pk.z = (unsigned)f2bf(v1.x) | ((unsigned)f2bf(v1.y) << 16);
    pk.w = (unsigned)f2bf(v1.z) | ((unsigned)f2bf(v1.w) << 16);
    *(uint4*)d = pk;
  }
  if (blockIdx.x != 0) return;
  for (int p = tid; p < 2304; p += 256) {
    uint32_t a = (uint32_t)p, bb = (uint32_t)(p + 2304);
    threefry2x32_k42(a, bb);
    int l0 = p / 18, j0 = p - l0 * 18;
    int p2 = p + 2304;
    int l1 = p2 / 18, j1 = p2 - l1 * 18;
    idxT[j0 * 256 + l0] = (int)(a & 0xFFu);
    idxT[j1 * 256 + l1] = (int)(bb & 0xFFu);
  }
  if (tid < 128) {
    float aq = 0.f, cq_ = 0.f, ak = 0.f, ck_ = 0.f, av = 0.f, cv_ = 0.f;
    for (int c = 0; c < 128; c++) {
      float w = mlp_w[c], bb = mlp_b[c];
      float q = wq[tid * 128 + c], k = wk[tid * 128 + c], v = wv[tid * 128 + c];
      aq += q * w; cq_ += q * bb;
      ak += k * w; ck_ += k * bb;
      av += v * w; cv_ += v * bb;
    }
    cst[0   + tid] = aq;
    cst[128 + tid] = cq_ + bq[tid];
    cst[256 + tid] = ak;
    cst[384 + tid] = ck_ + bk[tid];
    cst[512 + tid] = av;
    cst[640 + tid] = cv_ + bv[tid];
  }
  __syncthreads();
  if (tid < 8) {
    float a = 0.f, b = 0.f, g = 0.f, d = 0.f;
    for (int e = 0; e < 16; e++) {
      int j = tid * 16 + e;
      float Aq = cst[j], Cq = cst[128 + j], Ak = cst[256 + j], Ck = cst[384 + j];
      a += Aq * Ak; b += Aq * Ck; g += Cq * Ak; d += Cq * Ck;
    }
    cst[768 + tid] = a; cst[776 + tid] = b; cst[784 + tid] = g; cst[792 + tid] = d;
  }
  if (tid < 128) {
    float oc = 0.f;
    for (int h = 0; h < 8; h++) {
      float s = 0.f;
      for (int e = 0; e < 16; e++) {
        float w = wo[tid * 128 + h * 16 + e];
        s  += w * cst[512 + h * 16 + e];   // Av
        oc += w * cst[640 + h * 16 + e];   // cv
      }
      cst[800 + h * 128 + tid] = s;        // Wv[h][i]
    }
    cst[1824 + tid] = oc + bo[tid] + mlp_b[tid];  // ccol
  }
}

// ---------------------------------------------------------------------------
// Kernel B: per (seq, head-pair). score(l,s) = a*x_l*x_s + b*x_l + g*x_s + d.
// Top-18 via vectorized rank counting; softmax rows on half-wave groups.
// ---------------------------------------------------------------------------
__global__ __launch_bounds__(256) void attn_kernel(
    const float* __restrict__ x, const int* __restrict__ idxT,
    const float* __restrict__ cst, float* __restrict__ g) {
  __shared__ float xr[256];
  __shared__ float Mb[512];     // [hl][l]
  __shared__ float selv[512];   // [hl][l]
  __shared__ float rsum[4], rmax[4], rmin[4];
  __shared__ int   items[64];
  __shared__ float witem[64];
  __shared__ int   cnt;
  int tid = threadIdx.x, lane = tid & 63, w = tid >> 6;
  int seq = blockIdx.x >> 2, hg = blockIdx.x & 3;
  if (tid == 0) cnt = 0;
  float xv = x[seq * 256 + tid];
  xr[tid] = xv;
  float s = waveSum(xv);
  float mx = xv, mn = xv;
  #pragma unroll
  for (int m = 32; m > 0; m >>= 1) {
    mx = fmaxf(mx, __shfl_xor(mx, m));
    mn = fminf(mn, __shfl_xor(mn, m));
  }
  if (lane == 0) { rsum[w] = s; rmax[w] = mx; rmin[w] = mn; }
  __syncthreads();
  float meanx = (rsum[0] + rsum[1] + rsum[2] + rsum[3]) * (1.0f / 256.0f);
  float maxx = fmaxf(fmaxf(rmax[0], rmax[1]), fmaxf(rmax[2], rmax[3]));
  float minx = fminf(fminf(rmin[0], rmin[1]), fminf(rmin[2], rmin[3]));
  int l32 = tid & 31, grp = tid >> 5;
  float xs8[8];
  #pragma unroll
  for (int k = 0; k < 8; k++) xs8[k] = xr[l32 + k * 32];
  float mx18 = -INFINITY, mn18 = INFINITY, s18 = 0.f;
  #pragma unroll 3
  for (int j = 0; j < 18; j++) {
    float xs = xr[idxT[j * 256 + tid]];
    mx18 = fmaxf(mx18, xs); mn18 = fminf(mn18, xs); s18 += xs;
  }
  int h0 = hg * 2, h1 = h0 + 1;
  float al0 = cst[768 + h0], be0 = cst[776 + h0], ga0 = cst[784 + h0], de0 = cst[792 + h0];
  float al1 = cst[768 + h1], be1 = cst[776 + h1], ga1 = cst[784 + h1], de1 = cst[792 + h1];
  float ac0 = fmaf(al0, xv, ga0), cc0 = fmaf(be0, xv, de0);
  float ac1 = fmaf(al1, xv, ga1), cc1 = fmaf(be1, xv, de1);
  float M0 = ((ac0 >= 0.f ? ac0 * mx18 : ac0 * mn18) + cc0)
           - (fmaf(ac0, s18, 18.f * cc0)) * (1.0f / 256.0f);
  float M1 = ((ac1 >= 0.f ? ac1 * mx18 : ac1 * mn18) + cc1)
           - (fmaf(ac1, s18, 18.f * cc1)) * (1.0f / 256.0f);
  Mb[tid] = M0; Mb[256 + tid] = M1;
  __syncthreads();
  int r0 = 0, r1 = 0;
  const float4* Mb4 = (const float4*)Mb;
  #pragma unroll 4
  for (int j4 = 0; j4 < 64; j4++) {
    float4 a = Mb4[j4], bb = Mb4[64 + j4];
    int base = j4 * 4;
    r0 += (a.x > M0) || (a.x == M0 && base     < tid);
    r0 += (a.y > M0) || (a.y == M0 && base + 1 < tid);
    r0 += (a.z > M0) || (a.z == M0 && base + 2 < tid);
    r0 += (a.w > M0) || (a.w == M0 && base + 3 < tid);
    r1 += (bb.x > M1) || (bb.x == M1 && base     < tid);
    r1 += (bb.y > M1) || (bb.y == M1 && base + 1 < tid);
    r1 += (bb.z > M1) || (bb.z == M1 && base + 2 < tid);
    r1 += (bb.w > M1) || (bb.w == M1 && base + 3 < tid);
  }
  selv[tid] = meanx; selv[256 + tid] = meanx;
  if (r0 < 18) { int p = atomicAdd(&cnt, 1); items[p] = tid;       witem[p] = 0.25f * ac0; }
  if (r1 < 18) { int p = atomicAdd(&cnt, 1); items[p] = 256 + tid; witem[p] = 0.25f * ac1; }
  __syncthreads();
  int nIt = cnt;
  for (int i = grp; i < nIt; i += 8) {
    int it = items[i]; float wv = witem[i];
    float m0 = (wv >= 0.f) ? wv * maxx : wv * minx;
    float S1 = 0.f, Sx = 0.f;
    #pragma unroll
    for (int k = 0; k < 8; k++) {
      float e = __expf(fmaf(wv, xs8[k], -m0));
      S1 += e; Sx = fmaf(xs8[k], e, Sx);
    }
    #pragma unroll
    for (int m = 16; m > 0; m >>= 1) {
      S1 += __shfl_xor(S1, m); Sx += __shfl_xor(Sx, m);
    }
    if (l32 == 0) selv[it] = Sx / S1;
  }
  __syncthreads();
  float2 gv; gv.x = selv[tid]; gv.y = selv[256 + tid];
  *(float2*)&g[(size_t)((seq << 8) + tid) * 8 + hg * 2] = gv;
}

// ---------------------------------------------------------------------------
// Mega-kernel round 6: one block per (b, t), 32 rows (the N dim), 4 waves.
// Wave w owns f-slice [w*128,(w+1)*128): GEMM1 (all 32 rows) -> relu ->
// transpose via wave-PRIVATE LDS slot -> GEMM2 K-slice over full c=128.
// Weights read from FRAGMENT-ORDER buffers: every load = base+imm+lane*8,
// fully coalesced 1KB per instruction. Cross-wave K-partial reduce (bf16)
// in two phases through tbuf wave slots. 6 barriers total.
// MFMA 16x16x32 bf16: A[m=lane&15][k=quad*8+j], B[k=quad*8+j][n=lane&15],
// C/D: col=lane&15, row=quad*4+reg.
// ---------------------------------------------------------------------------
__global__ __launch_bounds__(256, 3) void mega_kernel(
    const float* __restrict__ x, const float* __restrict__ g,
    const float* __restrict__ cst, const float* __restrict__ mlp_w,
    const unsigned short* __restrict__ w1s, const float* __restrict__ b1,
    const unsigned short* __restrict__ w2s, const float* __restrict__ b2,
    const float* __restrict__ ln1g, const float* __restrict__ ln1b,
    const float* __restrict__ ln2g, const float* __restrict__ ln2b,
    float* __restrict__ out) {
  __shared__ unsigned short x1s[32 * 136];   // 8704 B (LN1 output, kept intact)
  __shared__ unsigned short tbuf[4 * 2304];  // 18432 B; transpose, then zred
  __shared__ float psum[512];                // 2048 B
  int tid = threadIdx.x, lane = tid & 63, w = tid >> 6;
  int col = lane & 15, quad = lane >> 4;
  int b = blockIdx.x >> 8, t = blockIdx.x & 255;
  unsigned short* tb = tbuf + w * 2304;

  // ---- LN1: wave w rows w*8..w*8+7, batched 4 rows for ILP ----
  {
    int c0 = lane << 1;
    float mwa = mlp_w[c0], mwb = mlp_w[c0 | 1];
    float cca = cst[1824 + c0], ccb = cst[1824 + (c0 | 1)];
    float wva[8], wvb[8];
    #pragma unroll
    for (int h = 0; h < 8; h++) {
      wva[h] = cst[800 + h * 128 + c0];
      wvb[h] = cst[800 + h * 128 + (c0 | 1)];
    }
    float g1a = ln1g[c0], g1b = ln1g[c0 | 1];
    float e1a = ln1b[c0], e1b = ln1b[c0 | 1];
    #pragma unroll
    for (int bt = 0; bt < 2; bt++) {
      float xv4[4]; float4 gA[4], gB[4];
      #pragma unroll
      for (int k = 0; k < 4; k++) {
        int n = w * 8 + bt * 4 + k;
        int tok = ((b * 32 + n) << 8) + t;
        xv4[k] = x[tok];
        gA[k] = *(const float4*)(g + (size_t)tok * 8);
        gB[k] = *(const float4*)(g + (size_t)tok * 8 + 4);
      }
      float ra[4], rb[4], su[4];
      #pragma unroll
      for (int k = 0; k < 4; k++) {
        float a_ = fmaf(xv4[k], mwa, cca), b_ = fmaf(xv4[k], mwb, ccb);
        a_ = fmaf(gA[k].x, wva[0], a_); b_ = fmaf(gA[k].x, wvb[0], b_);
        a_ = fmaf(gA[k].y, wva[1], a_); b_ = fmaf(gA[k].y, wvb[1], b_);
        a_ = fmaf(gA[k].z, wva[2], a_); b_ = fmaf(gA[k].z, wvb[2], b_);
        a_ = fmaf(gA[k].w, wva[3], a_); b_ = fmaf(gA[k].w, wvb[3], b_);
        a_ = fmaf(gB[k].x, wva[4], a_); b_ = fmaf(gB[k].x, wvb[4], b_);
        a_ = fmaf(gB[k].y, wva[5], a_); b_ = fmaf(gB[k].y, wvb[5], b_);
        a_ = fmaf(gB[k].z, wva[6], a_); b_ = fmaf(gB[k].z, wvb[6], b_);
        a_ = fmaf(gB[k].w, wva[7], a_); b_ = fmaf(gB[k].w, wvb[7], b_);
        ra[k] = a_; rb[k] = b_; su[k] = a_ + b_;
      }
      #pragma unroll
      for (int m = 32; m > 0; m >>= 1) {
        su[0] += __shfl_xor(su[0], m); su[1] += __shfl_xor(su[1], m);
        su[2] += __shfl_xor(su[2], m); su[3] += __shfl_xor(su[3], m);
      }
      float vs[4], da[4], db[4];
      #pragma unroll
      for (int k = 0; k < 4; k++) {
        float mu = su[k] * (1.0f / 128.0f);
        da[k] = ra[k] - mu; db[k] = rb[k] - mu;
        vs[k] = da[k] * da[k] + db[k] * db[k];
      }
      #pragma unroll
      for (int m = 32; m > 0; m >>= 1) {
        vs[0] += __shfl_xor(vs[0], m); vs[1] += __shfl_xor(vs[1], m);
        vs[2] += __shfl_xor(vs[2], m); vs[3] += __shfl_xor(vs[3], m);
      }
      #pragma unroll
      for (int k = 0; k < 4; k++) {
        int n = w * 8 + bt * 4 + k;
        float inv = rsqrtf(vs[k] * (1.0f / 128.0f) + EPSF);
        unsigned int pa = f2bf(da[k] * inv * g1a + e1a);
        unsigned int pb = f2bf(db[k] * inv * g1b + e1b);
        *(unsigned int*)&x1s[n * 136 + c0] = pa | (pb << 16);
      }
    }
  }
  __syncthreads();   // x1s complete

  // ---- wave-private GEMM1 -> relu -> transpose -> GEMM2 (K-split) ----
  float b1v[2][4];
  #pragma unroll
  for (int ch = 0; ch < 2; ch++)
    #pragma unroll
    for (int ft = 0; ft < 4; ft++)
      b1v[ch][ft] = b1[w * 128 + ch * 64 + ft * 16 + col];

  f32x4 acc2[2][8];
  #pragma unroll
  for (int i = 0; i < 2; i++)
    #pragma unroll
    for (int j = 0; j < 8; j++) acc2[i][j] = (f32x4){0.f, 0.f, 0.f, 0.f};

  #pragma unroll
  for (int ch = 0; ch < 2; ch++) {
    // fragment-order weight bases for this (wave, chunk)
    const unsigned short* w1p = w1s + (w * 2 + ch) * 8192 + lane * 8;
    const unsigned short* w2p = w2s + (w * 2 + ch) * 8192 + lane * 8;
    f32x4 acc1[2][4];
    #pragma unroll
    for (int i = 0; i < 2; i++)
      #pragma unroll
      for (int j = 0; j < 4; j++) acc1[i][j] = (f32x4){0.f, 0.f, 0.f, 0.f};
    #pragma unroll
    for (int ks = 0; ks < 4; ks++) {
      bf16x8 a0 = *(const bf16x8*)&x1s[col * 136 + ks * 32 + quad * 8];
      bf16x8 a1 = *(const bf16x8*)&x1s[(16 + col) * 136 + ks * 32 + quad * 8];
      #pragma unroll
      for (int ft = 0; ft < 4; ft++) {
        bf16x8 bw = *(const bf16x8*)(w1p + ks * 2048 + ft * 512);
        acc1[0][ft] = __builtin_amdgcn_mfma_f32_16x16x32_bf16(a0, bw, acc1[0][ft], 0, 0, 0);
        acc1[1][ft] = __builtin_amdgcn_mfma_f32_16x16x32_bf16(a1, bw, acc1[1][ft], 0, 0, 0);
      }
    }
    // relu + bias -> wave-private transpose slot (C-layout -> A-layout)
    #pragma unroll
    for (int ft = 0; ft < 4; ft++) {
      #pragma unroll
      for (int rg = 0; rg < 2; rg++) {
        #pragma unroll
        for (int r = 0; r < 4; r++) {
          float vv = fmaxf(acc1[rg][ft][r] + b1v[ch][ft], 0.f);
          tb[(rg * 16 + quad * 4 + r) * 72 + ft * 16 + col] = f2bf(vv);
        }
      }
    }
    // GEMM2 partial: K-slice = this wave's f-slice chunk, full c=128
    #pragma unroll
    for (int kk = 0; kk < 2; kk++) {
      bf16x8 a0 = *(const bf16x8*)&tb[col * 72 + kk * 32 + quad * 8];
      bf16x8 a1 = *(const bf16x8*)&tb[(16 + col) * 72 + kk * 32 + quad * 8];
      #pragma unroll
      for (int tc = 0; tc < 8; tc++) {
        bf16x8 bw = *(const bf16x8*)(w2p + kk * 4096 + tc * 512);
        acc2[0][tc] = __builtin_amdgcn_mfma_f32_16x16x32_bf16(a0, bw, acc2[0][tc], 0, 0, 0);
        acc2[1][tc] = __builtin_amdgcn_mfma_f32_16x16x32_bf16(a1, bw, acc2[1][tc], 0, 0, 0);
      }
    }
  }

  // ---- epilogue: two-phase cross-wave K-partial reduce + LN2 + n-sum ----
  int row16 = tid >> 4, c8 = (tid & 15) << 3;
  float b2v[8], g2v[8], e2v[8];
  {
    float4 a0 = *(const float4*)(b2 + c8),  a1 = *(const float4*)(b2 + c8 + 4);
    float4 b0 = *(const float4*)(ln2g + c8), b1_ = *(const float4*)(ln2g + c8 + 4);
    float4 c0 = *(const float4*)(ln2b + c8), c1 = *(const float4*)(ln2b + c8 + 4);
    b2v[0]=a0.x; b2v[1]=a0.y; b2v[2]=a0.z; b2v[3]=a0.w;
    b2v[4]=a1.x; b2v[5]=a1.y; b2v[6]=a1.z; b2v[7]=a1.w;
    g2v[0]=b0.x; g2v[1]=b0.y; g2v[2]=b0.z; g2v[3]=b0.w;
    g2v[4]=b1_.x; g2v[5]=b1_.y; g2v[6]=b1_.z; g2v[7]=b1_.w;
    e2v[0]=c0.x; e2v[1]=c0.y; e2v[2]=c0.z; e2v[3]=c0.w;
    e2v[4]=c1.x; e2v[5]=c1.y; e2v[6]=c1.z; e2v[7]=c1.w;
  }
  // residual (x1s is never overwritten; safe without extra barriers)
  float res[2][8];
  #pragma unroll
  for (int p = 0; p < 2; p++) {
    bf16x8 rv = *(const bf16x8*)&x1s[(p * 16 + row16) * 136 + c8];
    #pragma unroll
    for (int k = 0; k < 8; k++) res[p][k] = bf2f((unsigned short)rv[k]);
  }

  #pragma unroll
  for (int p = 0; p < 2; p++) {
    if (p) __syncthreads();   // phase-0 reads of tbuf done before overwrite
    // write this wave's partial for rows p*16..p*16+15 (local rows 0..15)
    #pragma unroll
    for (int tc = 0; tc < 8; tc++) {
      #pragma unroll
      for (int r = 0; r < 4; r++)
        tb[(quad * 4 + r) * 136 + tc * 16 + col] = f2bf(acc2[p][tc][r]);
    }
    __syncthreads();          // all 4 wave-partials visible
    float z[8];
    #pragma unroll
    for (int k = 0; k < 8; k++) z[k] = b2v[k] + res[p][k];
    #pragma unroll
    for (int ws = 0; ws < 4; ws++) {
      bf16x8 v = *(const bf16x8*)&tbuf[ws * 2304 + row16 * 136 + c8];
      #pragma unroll
      for (int k = 0; k < 8; k++) z[k] += bf2f((unsigned short)v[k]);
    }
    float s = 0.f;
    #pragma unroll
    for (int k = 0; k < 8; k++) s += z[k];
    #pragma unroll
    for (int m = 1; m <= 8; m <<= 1) s += __shfl_xor(s, m);
    float mu = s * (1.0f / 128.0f);
    float q = 0.f;
    #pragma unroll
    for (int k = 0; k < 8; k++) { float d = z[k] - mu; q += d * d; }
    #pragma unroll
    for (int m = 1; m <= 8; m <<= 1) q += __shfl_xor(q, m);
    float inv = rsqrtf(q * (1.0f / 128.0f) + EPSF);
    float o[8];
    #pragma unroll
    for (int k = 0; k < 8; k++) o[k] = (z[k] - mu) * inv * g2v[k] + e2v[k];
    // sum over this wave's 4 rows (lane bits 16, 32)
    #pragma unroll
    for (int k = 0; k < 8; k++) {
      o[k] += __shfl_xor(o[k], 16);
      o[k] += __shfl_xor(o[k], 32);
    }
    if (lane < 16) {
      float* pp = &psum[w * 128 + lane * 8];
      if (p == 0) {
        #pragma unroll
        for (int k = 0; k < 8; k++) pp[k] = o[k];
      } else {
        #pragma unroll
        for (int k = 0; k < 8; k++) pp[k] += o[k];
      }
    }
  }
  __syncthreads();
  if (tid < 128) {
    float v = psum[tid] + psum[128 + tid] + psum[256 + tid] + psum[384 + tid];
    out[(size_t)(b * 128 + tid) * 256 + t] = v;
  }
}

// ---------------------------------------------------------------------------
extern "C" void kernel_launch(void* const* d_in, const int* in_sizes, int n_in,
                              void* d_out, int out_size, void* d_ws, size_t ws_size,
                              hipStream_t stream) {
  (void)in_sizes; (void)n_in; (void)out_size; (void)ws_size;
  const float* x    = (const float*)d_in[0];
  const float* mlpw = (const float*)d_in[1];
  const float* mlpb = (const float*)d_in[2];
  const float* wq   = (const float*)d_in[3];
  const float* bq   = (const float*)d_in[4];
  const float* wk   = (const float*)d_in[5];
  const float* bk   = (const float*)d_in[6];
  const float* wv   = (const float*)d_in[7];
  const float* bv   = (const float*)d_in[8];
  const float* wo   = (const float*)d_in[9];
  const float* bo   = (const float*)d_in[10];
  const float* w1   = (const float*)d_in[11];
  const float* b1   = (const float*)d_in[12];
  const float* w2   = (const float*)d_in[13];
  const float* b2   = (const float*)d_in[14];
  const float* ln1g = (const float*)d_in[15];
  const float* ln1b = (const float*)d_in[16];
  const float* ln2g = (const float*)d_in[17];
  const float* ln2b = (const float*)d_in[18];

  char* ws = (char*)d_ws;
  int*            idxT = (int*)(ws);                       // 18,432 B
  float*          cst  = (float*)(ws + 20480);             //  7,808 B
  unsigned short* w1s  = (unsigned short*)(ws + 32768);    // 131,072 B
  unsigned short* w2s  = (unsigned short*)(ws + 163840);   // 131,072 B
  float*          gbuf = (float*)(ws + 294912);            // 1 MB
  float*          outp = (float*)d_out;

  hipLaunchKernelGGL(setup_kernel, dim3(64), dim3(256), 0, stream,
                     mlpw, mlpb, wq, bq, wk, bk, wv, bv, wo, bo, w1, w2,
                     idxT, cst, w1s, w2s);
  hipLaunchKernelGGL(attn_kernel, dim3(512), dim3(256), 0, stream,
                     x, idxT, cst, gbuf);
  hipLaunchKernelGGL(mega_kernel, dim3(1024), dim3(256), 0, stream,
                     x, gbuf, cst, mlpw, w1s, b1, w2s, b2,
                     ln1g, ln1b, ln2g, ln2b, outp);
}